// Round 5
// baseline (949.708 us; speedup 1.0000x reference)
//
#include <hip/hip_runtime.h>
#include <hip/hip_bf16.h>
#include <cmath>

#define N0 50000
#define NEDGE 800000
#define NEG_HUGE -3.402823466e38f
#define BMAX 64
#define STRIDE 128   // max degree slots per node (Poisson(16): P(deg>=128) ~ 0)

// ---------- helpers ----------
__device__ inline float b2f(unsigned short u) { return __uint_as_float(((unsigned)u) << 16); }

__device__ inline unsigned short f2b(float f) {
    __hip_bfloat16 h = __float2bfloat16(f);
    return *(unsigned short*)&h;
}

__device__ inline unsigned fkey(float f) {
    unsigned b = __float_as_uint(f);
    if (b == 0x80000000u) b = 0u;  // canonicalize -0 -> +0
    return (b & 0x80000000u) ? ~b : (b | 0x80000000u);
}

__device__ inline void atomicMaxF(float* a, float v) {
    if (v >= 0.f) atomicMax((int*)a, __float_as_int(v));
    else          atomicMin((unsigned int*)a, __float_as_uint(v));
}

// ---------- init: copy edges, zero accumulators / deg / bins ----------
__global__ void k_init(const int* __restrict__ src, const int* __restrict__ dst,
                       int* cur_src, int* cur_dst, float* finalv,
                       int* deg_out, int* fill, int* gbins) {
    int i = blockIdx.x * blockDim.x + threadIdx.x;
    if (i < NEDGE) { cur_src[i] = src[i]; cur_dst[i] = dst[i]; }
    if (i < 256) finalv[i] = 0.f;
    if (i < N0) { deg_out[i] = 0; fill[i] = 0; }
    if (i < 65536) gbins[i] = 0;
}

// ---------- fused remap + degree count + CSR fill (fixed stride) ----------
__global__ void k_fillrm(int* cur_src, int* cur_dst, const int* __restrict__ newid,
                         int do_remap, int* deg_out, int* fill, int* csr_src) {
    int e = blockIdx.x * blockDim.x + threadIdx.x;
    if (e >= NEDGE) return;
    int s = cur_src[e];
    if (s < 0) return;
    int d = cur_dst[e];
    if (do_remap) {
        int ns = newid[s], nd = newid[d];
        if (ns < 0 || nd < 0) { cur_src[e] = -1; return; }
        s = ns; d = nd;
        cur_src[e] = s; cur_dst[e] = d;
    }
    atomicAdd(&deg_out[s], 1);
    int pos = atomicAdd(&fill[d], 1);
    if (pos < STRIDE) csr_src[(size_t)d * STRIDE + pos] = s;
}

// ---------- GEMM: h_pre(bf16) = X @ W ----------
// mode 0: X = feat (fp32). mode 1: X[r] = xprev[oldid[r]] * garr[r].
__global__ __launch_bounds__(256) void k_gemm(
        const float* __restrict__ feat, const float* __restrict__ xprev,
        const int* __restrict__ oldid, const float* __restrict__ garr,
        const float* __restrict__ W, unsigned short* __restrict__ hpre,
        int n, int nprev, int mode) {
    __shared__ float Wt[32][132];
    __shared__ float Xt[64][33];
    int tid = threadIdx.x;
    int r0 = blockIdx.x * 64;
    int c0 = (tid & 7) * 16;
    int rl0 = (tid >> 3) * 2;
    float acc0[16], acc1[16];
#pragma unroll
    for (int c = 0; c < 16; ++c) { acc0[c] = 0.f; acc1[c] = 0.f; }

    for (int kb = 0; kb < 128; kb += 32) {
        {
            int kk = tid >> 3;
            int cc = (tid & 7) * 16;
            const float4* wp = (const float4*)(W + (size_t)(kb + kk) * 128 + cc);
            float4 w0 = wp[0], w1 = wp[1], w2 = wp[2], w3 = wp[3];
            float* dw = &Wt[kk][cc];
            dw[0] = w0.x; dw[1] = w0.y; dw[2] = w0.z; dw[3] = w0.w;
            dw[4] = w1.x; dw[5] = w1.y; dw[6] = w1.z; dw[7] = w1.w;
            dw[8] = w2.x; dw[9] = w2.y; dw[10] = w2.z; dw[11] = w2.w;
            dw[12] = w3.x; dw[13] = w3.y; dw[14] = w3.z; dw[15] = w3.w;
        }
        {
            int rr = tid >> 2;
            int kx = (tid & 3) * 8;
            int gr = r0 + rr;
            float vals[8];
            if (gr < n) {
                if (mode == 0) {
                    const float4* xp = (const float4*)(feat + (size_t)gr * 128 + kb + kx);
                    float4 a = xp[0], bq = xp[1];
                    vals[0] = a.x; vals[1] = a.y; vals[2] = a.z; vals[3] = a.w;
                    vals[4] = bq.x; vals[5] = bq.y; vals[6] = bq.z; vals[7] = bq.w;
                } else {
                    int orow = oldid[gr];
                    float g = garr[gr];
                    if ((unsigned)orow >= (unsigned)nprev) { orow = 0; g = 0.f; }
                    const float4* xp = (const float4*)(xprev + (size_t)orow * 128 + kb + kx);
                    float4 a = xp[0], bq = xp[1];
                    vals[0] = a.x * g; vals[1] = a.y * g; vals[2] = a.z * g; vals[3] = a.w * g;
                    vals[4] = bq.x * g; vals[5] = bq.y * g; vals[6] = bq.z * g; vals[7] = bq.w * g;
                }
            } else {
#pragma unroll
                for (int q2 = 0; q2 < 8; ++q2) vals[q2] = 0.f;
            }
            float* dx = &Xt[rr][kx];
#pragma unroll
            for (int q2 = 0; q2 < 8; ++q2) dx[q2] = vals[q2];
        }
        __syncthreads();
#pragma unroll 4
        for (int kk = 0; kk < 32; ++kk) {
            float x0 = Xt[rl0][kk], x1 = Xt[rl0 + 1][kk];
#pragma unroll
            for (int c = 0; c < 16; ++c) {
                float wv = Wt[kk][c0 + c];
                acc0[c] = fmaf(x0, wv, acc0[c]);
                acc1[c] = fmaf(x1, wv, acc1[c]);
            }
        }
        __syncthreads();
    }
    int gr0 = r0 + rl0;
    if (gr0 < n) {
        unsigned short tmp[16];
#pragma unroll
        for (int c = 0; c < 16; ++c) tmp[c] = f2b(acc0[c]);
        uint4* op = (uint4*)(hpre + (size_t)gr0 * 128 + c0);
        op[0] = ((uint4*)tmp)[0]; op[1] = ((uint4*)tmp)[1];
    }
    int gr1 = gr0 + 1;
    if (gr1 < n) {
        unsigned short tmp[16];
#pragma unroll
        for (int c = 0; c < 16; ++c) tmp[c] = f2b(acc1[c]);
        uint4* op = (uint4*)(hpre + (size_t)gr1 * 128 + c0);
        op[0] = ((uint4*)tmp)[0]; op[1] = ((uint4*)tmp)[1];
    }
}

// ---------- edge aggregation (bf16 gather, fp32 accumulate) ----------
// h_post[d] = relu(nd[d]*sum_in h_pre[s]*ns[s] + cb); hs[d] = h_post[d].sW
__global__ __launch_bounds__(256) void k_agg_conv(
        const unsigned short* __restrict__ hpre, const int* __restrict__ fill,
        const int* __restrict__ deg_out, const int* __restrict__ csr_src,
        const float* __restrict__ cb, const float* __restrict__ sW,
        float* __restrict__ hpost, float* __restrict__ hs, int n) {
    int wid = threadIdx.x >> 6;
    int lane = threadIdx.x & 63;
    int d = blockIdx.x * 4 + wid;
    if (d >= n) return;
    int degin = fill[d];
    int cnt = min(degin, STRIDE);
    const int* bp = csr_src + (size_t)d * STRIDE;
    float a0 = 0.f, a1 = 0.f;
    int j = 0;
    for (; j + 2 <= cnt; j += 2) {
        int s0 = bp[j], s1 = bp[j + 1];
        float w0 = rsqrtf(fmaxf((float)deg_out[s0], 1.f));
        float w1 = rsqrtf(fmaxf((float)deg_out[s1], 1.f));
        ushort2 u0 = ((const ushort2*)(hpre + (size_t)s0 * 128))[lane];
        ushort2 u1 = ((const ushort2*)(hpre + (size_t)s1 * 128))[lane];
        a0 = fmaf(b2f(u0.x), w0, a0); a0 = fmaf(b2f(u1.x), w1, a0);
        a1 = fmaf(b2f(u0.y), w0, a1); a1 = fmaf(b2f(u1.y), w1, a1);
    }
    if (j < cnt) {
        int s0 = bp[j];
        float w0 = rsqrtf(fmaxf((float)deg_out[s0], 1.f));
        ushort2 u0 = ((const ushort2*)(hpre + (size_t)s0 * 128))[lane];
        a0 = fmaf(b2f(u0.x), w0, a0);
        a1 = fmaf(b2f(u0.y), w0, a1);
    }
    float nd2 = rsqrtf(fmaxf((float)degin, 1.f));
    int c0 = lane * 2;
    float h0 = fmaxf(fmaf(a0, nd2, cb[c0]), 0.f);
    float h1 = fmaxf(fmaf(a1, nd2, cb[c0 + 1]), 0.f);
    ((float2*)(hpost + (size_t)d * 128))[lane] = make_float2(h0, h1);
    float v = h0 * sW[c0] + h1 * sW[c0 + 1];
#pragma unroll
    for (int off = 32; off; off >>= 1) v += __shfl_down(v, off);
    if (lane == 0) hs[d] = v;
}

// ---------- score + radix histogram pass 1 (top 16 bits) fused ----------
__global__ void k_score_hist(const float* __restrict__ hs, const int* __restrict__ fill,
                             const int* __restrict__ deg_out, const int* __restrict__ csr_src,
                             const float* __restrict__ sb, float* score, int* gbins, int n) {
    int d = blockIdx.x * blockDim.x + threadIdx.x;
    if (d >= n) return;
    int degin = fill[d];
    int cnt = min(degin, STRIDE);
    const int* bp = csr_src + (size_t)d * STRIDE;
    float sum = 0.f;
    for (int j = 0; j < cnt; ++j) {
        int s = bp[j];
        sum = fmaf(hs[s], rsqrtf(fmaxf((float)deg_out[s], 1.f)), sum);
    }
    float sc = rsqrtf(fmaxf((float)degin, 1.f)) * sum + sb[0];
    score[d] = sc;
    atomicAdd(&gbins[fkey(sc) >> 16], 1);
}

// ---------- radix pick (stage 0: high 16 bits; stage 1: low 16 bits) ----------
// ctrl[0]=T  ctrl[2]=needEq  ctrl[3]=prefix16  ctrl[4]=kneed2
__global__ void k_rpick(int stage, int k0, int* ctrl, int* gbins) {
    __shared__ int csum[1024];
    int t = threadIdx.x;  // 1024
    int base = t * 64;
    int s = 0;
#pragma unroll
    for (int i = 0; i < 64; ++i) s += gbins[base + i];
    csum[t] = s;
    __syncthreads();
    if (t == 0) {
        int kneed = (stage == 0) ? k0 : ctrl[4];
        int cum = 0, tc = 1023;
        for (; tc >= 1; --tc) { int c = csum[tc]; if (cum + c >= kneed) break; cum += c; }
        int d = 63;
        for (; d >= 1; --d) { int c = gbins[tc * 64 + d]; if (cum + c >= kneed) break; cum += c; }
        int binidx = tc * 64 + d;
        if (stage == 0) { ctrl[3] = binidx; ctrl[4] = kneed - cum; }
        else {
            unsigned T = (((unsigned)ctrl[3]) << 16) | (unsigned)binidx;
            ctrl[0] = (int)T; ctrl[2] = kneed - cum;
        }
    }
    __syncthreads();
#pragma unroll
    for (int i = 0; i < 64; ++i) gbins[base + i] = 0;
}

// ---------- radix histogram pass 2 (low 16 bits of matching prefix) ----------
__global__ void k_rhist2(const float* __restrict__ score, const int* __restrict__ ctrl,
                         int n, int* gbins) {
    unsigned p16 = (unsigned)ctrl[3];
    for (int i = blockIdx.x * 256 + threadIdx.x; i < n; i += gridDim.x * 256) {
        unsigned u = fkey(score[i]);
        if ((u >> 16) == p16) atomicAdd(&gbins[u & 0xFFFFu], 1);
    }
}

// ---------- parallel compaction ----------
__global__ void k_ccnt(const float* __restrict__ score, const int* __restrict__ ctrl,
                       int n, int* cntG, int* cntE) {
    __shared__ int wG[16], wE[16];
    int b = blockIdx.x;
    int i = b * 1024 + threadIdx.x;
    int lane = threadIdx.x & 63, wid = threadIdx.x >> 6;
    unsigned T = (unsigned)ctrl[0];
    bool inb = (i < n);
    unsigned u = inb ? fkey(score[i]) : 0u;
    bool isG = inb && (u > T);
    bool isE = inb && (u == T);
    unsigned long long mG = __ballot(isG);
    unsigned long long mE = __ballot(isE);
    if (lane == 0) { wG[wid] = __popcll(mG); wE[wid] = __popcll(mE); }
    __syncthreads();
    if (threadIdx.x == 0) {
        int sg = 0, se = 0;
#pragma unroll
        for (int w = 0; w < 16; ++w) { sg += wG[w]; se += wE[w]; }
        cntG[b] = sg; cntE[b] = se;
    }
}

__global__ void k_cscan(const int* __restrict__ cntG, const int* __restrict__ cntE,
                        int* coffG, int* coffE, int B, float* maxbuf) {
    int tid = threadIdx.x;  // 256
    if (tid < 128) maxbuf[tid] = NEG_HUGE;
    if (tid == 0) {
        int rg = 0, re = 0;
        for (int b = 0; b < B; ++b) {
            coffG[b] = rg; coffE[b] = re;
            rg += cntG[b]; re += cntE[b];
        }
    }
}

// emit + zero next-level degree arrays
__global__ void k_cemit(const float* __restrict__ score, const int* __restrict__ ctrl,
                        const int* __restrict__ coffG, const int* __restrict__ coffE,
                        int n, int knext, int* newid, int* oldid, float* garr,
                        int* deg_out, int* fill) {
    __shared__ int wG[16], wE[16];
    int b = blockIdx.x;
    int i = b * 1024 + threadIdx.x;
    if (i < knext) { deg_out[i] = 0; fill[i] = 0; }
    int lane = threadIdx.x & 63, wid = threadIdx.x >> 6;
    unsigned T = (unsigned)ctrl[0];
    int needEq = ctrl[2];
    bool inb = (i < n);
    float sc = inb ? score[i] : 0.f;
    unsigned u = inb ? fkey(sc) : 0u;
    bool isG = inb && (u > T);
    bool isE = inb && (u == T);
    unsigned long long mG = __ballot(isG);
    unsigned long long mE = __ballot(isE);
    if (lane == 0) { wG[wid] = __popcll(mG); wE[wid] = __popcll(mE); }
    __syncthreads();
    unsigned long long below = (1ull << lane) - 1ull;
    int gW = 0, eW = 0;
    for (int w = 0; w < wid; ++w) { gW += wG[w]; eW += wE[w]; }
    int Gb = coffG[b] + gW + __popcll(mG & below);
    int Eb = coffE[b] + eW + __popcll(mE & below);
    if (inb) {
        bool sel = isG || (isE && (Eb < needEq));
        if (sel) {
            int j = Gb + min(Eb, needEq);
            newid[i] = j;
            oldid[j] = i;
            garr[j] = tanhf(sc);
        } else {
            newid[i] = -1;
        }
    }
}

__global__ void k_readout(const float* __restrict__ hpost, const int* __restrict__ oldid,
                          const float* __restrict__ garr, float* finalv, float* maxbuf,
                          int k, int n, float invk) {
    int c = threadIdx.x;  // 128
    float sum = 0.f, mx = NEG_HUGE;
    for (int r = blockIdx.x; r < k; r += gridDim.x) {
        int o = oldid[r];
        if ((unsigned)o >= (unsigned)n) continue;  // insurance
        float g = garr[r];
        float v = hpost[(size_t)o * 128 + c] * g;
        sum += v;
        mx = fmaxf(mx, v);
    }
    atomicAdd(&finalv[c], sum * invk);
    atomicMaxF(&maxbuf[c], mx);
}

// ---------- fused 3-layer MLP (single block, 256 threads) ----------
__global__ __launch_bounds__(256) void k_mlp(
        const float* __restrict__ finalv, const float* __restrict__ maxbuf,  // 3 x 128
        const float* __restrict__ seq,
        const float* __restrict__ W1, const float* __restrict__ b1,
        const float* __restrict__ W2, const float* __restrict__ bb2,
        const float* __restrict__ W3, const float* __restrict__ b3,
        float* __restrict__ out) {
    __shared__ float in[1280];
    __shared__ float f1s[256];
    __shared__ float f2s[128];
    int t = threadIdx.x;  // 256
    for (int idx = t; idx < 1280; idx += 256) {
        float v;
        if (idx < 128) v = finalv[idx];
        else if (idx < 256) {
            int j = idx - 128;
            v = maxbuf[j] + maxbuf[128 + j] + maxbuf[256 + j];
        } else v = seq[idx - 256];
        in[idx] = v;
    }
    __syncthreads();
    {
        float acc = 0.f;
        for (int j = 0; j < 1280; ++j) acc = fmaf(in[j], W1[(size_t)j * 256 + t], acc);
        f1s[t] = fmaxf(acc + b1[t], 0.f);
    }
    __syncthreads();
    if (t < 128) {
        float acc = 0.f;
        for (int j = 0; j < 256; ++j) acc = fmaf(f1s[j], W2[(size_t)j * 128 + t], acc);
        f2s[t] = fmaxf(acc + bb2[t], 0.f);
    }
    __syncthreads();
#pragma unroll
    for (int q = 0; q < 8; ++q) {
        int col = t + q * 256;
        float acc = 0.f;
        for (int j = 0; j < 128; ++j) acc = fmaf(f2s[j], W3[(size_t)j * 2048 + col], acc);
        out[col] = acc + b3[col];
    }
}

// ---------- host ----------
extern "C" void kernel_launch(void* const* d_in, const int* in_sizes, int n_in,
                              void* d_out, int out_size, void* d_ws, size_t ws_size,
                              hipStream_t stream) {
    (void)in_sizes; (void)n_in; (void)out_size; (void)ws_size;
    const float* feat = (const float*)d_in[0];
    const float* seq  = (const float*)d_in[1];
    const int* src = (const int*)d_in[2];
    const int* dst = (const int*)d_in[3];
    // d_in[4], d_in[5]: label_src/label_dst — dead code in reference, unused.
    const float *cW[3], *cb[3], *sW[3], *sb[3];
    for (int b = 0; b < 3; ++b) {
        cW[b] = (const float*)d_in[6 + 4 * b];
        cb[b] = (const float*)d_in[7 + 4 * b];
        sW[b] = (const float*)d_in[8 + 4 * b];
        sb[b] = (const float*)d_in[9 + 4 * b];
    }
    const float* lin1W = (const float*)d_in[18];
    const float* lin1b = (const float*)d_in[19];
    const float* lin2W = (const float*)d_in[20];
    const float* lin2b = (const float*)d_in[21];
    const float* lin3W = (const float*)d_in[22];
    const float* lin3b = (const float*)d_in[23];
    float* out = (float*)d_out;

    char* p = (char*)d_ws;
    size_t off = 0;
    auto alloc = [&](size_t bytes) -> void* {
        void* r = p + off;
        off = (off + bytes + 255) & ~(size_t)255;
        return r;
    };
    unsigned short* hpre = (unsigned short*)alloc((size_t)N0 * 128 * 2);  // bf16
    float* hpost  = (float*)alloc((size_t)N0 * 128 * 4);
    float* hs     = (float*)alloc((size_t)N0 * 4);
    float* score  = (float*)alloc((size_t)N0 * 4);
    int* deg_out  = (int*)alloc((size_t)N0 * 4);
    int* fill     = (int*)alloc((size_t)N0 * 4);   // = in-degree
    int* cur_src  = (int*)alloc((size_t)NEDGE * 4);
    int* cur_dst  = (int*)alloc((size_t)NEDGE * 4);
    int* csr_src  = (int*)alloc((size_t)N0 * STRIDE * 4);
    int* newid    = (int*)alloc((size_t)N0 * 4);
    int* oldid    = (int*)alloc((size_t)25000 * 4);
    float* garr   = (float*)alloc((size_t)25000 * 4);
    float* maxbuf = (float*)alloc(3 * 128 * 4);
    float* finalv = (float*)alloc(256 * 4);
    int* ctrl     = (int*)alloc(64 * 4);
    int* gbins    = (int*)alloc(65536 * 4);
    int* cntG     = (int*)alloc(BMAX * 4);
    int* cntE     = (int*)alloc(BMAX * 4);
    int* coffG    = (int*)alloc(BMAX * 4);
    int* coffE    = (int*)alloc(BMAX * 4);

    const int nb[3] = {50000, 25000, 12500};
    const int kb[3] = {25000, 12500, 6250};

    k_init<<<(NEDGE + 255) / 256, 256, 0, stream>>>(src, dst, cur_src, cur_dst, finalv,
                                                    deg_out, fill, gbins);

    for (int b = 0; b < 3; ++b) {
        int n = nb[b], k = kb[b];
        int B = (n + 1023) / 1024;
        k_fillrm<<<(NEDGE + 255) / 256, 256, 0, stream>>>(cur_src, cur_dst, newid,
                                                          (b > 0) ? 1 : 0, deg_out, fill, csr_src);
        k_gemm<<<(n + 63) / 64, 256, 0, stream>>>(feat, hpost, oldid, garr, cW[b], hpre, n,
                                                  (b > 0) ? nb[b - 1] : 1, (b == 0) ? 0 : 1);
        k_agg_conv<<<(n + 3) / 4, 256, 0, stream>>>(hpre, fill, deg_out, csr_src, cb[b],
                                                    sW[b], hpost, hs, n);
        k_score_hist<<<(n + 255) / 256, 256, 0, stream>>>(hs, fill, deg_out, csr_src, sb[b],
                                                          score, gbins, n);
        k_rpick<<<1, 1024, 0, stream>>>(0, k, ctrl, gbins);
        k_rhist2<<<128, 256, 0, stream>>>(score, ctrl, n, gbins);
        k_rpick<<<1, 1024, 0, stream>>>(1, k, ctrl, gbins);
        k_ccnt<<<B, 1024, 0, stream>>>(score, ctrl, n, cntG, cntE);
        k_cscan<<<1, 256, 0, stream>>>(cntG, cntE, coffG, coffE, B, maxbuf + b * 128);
        k_cemit<<<B, 1024, 0, stream>>>(score, ctrl, coffG, coffE, n, (b < 2) ? kb[b] : 0,
                                        newid, oldid, garr, deg_out, fill);
        k_readout<<<256, 128, 0, stream>>>(hpost, oldid, garr, finalv, maxbuf + b * 128,
                                           k, n, 1.0f / (float)k);
    }

    k_mlp<<<1, 256, 0, stream>>>(finalv, maxbuf, seq, lin1W, lin1b, lin2W, lin2b,
                                 lin3W, lin3b, out);
}

// Round 6
// 678.713 us; speedup vs baseline: 1.3993x; 1.3993x over previous
//
#include <hip/hip_runtime.h>
#include <hip/hip_bf16.h>
#include <cmath>

#define N0 50000
#define NEDGE 800000
#define NEG_HUGE -3.402823466e38f
#define BMAX 64
#define STRIDE 128   // max degree slots per node (Poisson(16): P(deg>=128) ~ 0)

// ---------- helpers ----------
__device__ inline float b2f(unsigned short u) { return __uint_as_float(((unsigned)u) << 16); }

__device__ inline unsigned short f2b(float f) {
    __hip_bfloat16 h = __float2bfloat16(f);
    return *(unsigned short*)&h;
}

__device__ inline unsigned fkey(float f) {
    unsigned b = __float_as_uint(f);
    if (b == 0x80000000u) b = 0u;  // canonicalize -0 -> +0
    return (b & 0x80000000u) ? ~b : (b | 0x80000000u);
}

__device__ inline void atomicMaxF(float* a, float v) {
    if (v >= 0.f) atomicMax((int*)a, __float_as_int(v));
    else          atomicMin((unsigned int*)a, __float_as_uint(v));
}

// ---------- init: copy edges, zero accumulators / deg ----------
__global__ void k_init(const int* __restrict__ src, const int* __restrict__ dst,
                       int* cur_src, int* cur_dst, float* finalv, float* f1raw,
                       int* deg_out, int* fill) {
    int i = blockIdx.x * blockDim.x + threadIdx.x;
    if (i < NEDGE) { cur_src[i] = src[i]; cur_dst[i] = dst[i]; }
    if (i < 256) { finalv[i] = 0.f; f1raw[i] = 0.f; }
    if (i < N0) { deg_out[i] = 0; fill[i] = 0; }
}

// ---------- fused remap + degree count + CSR fill + bins zero ----------
__global__ void k_fillrm(int* cur_src, int* cur_dst, const int* __restrict__ newid,
                         int do_remap, int* deg_out, int* fill, int* csr_src,
                         int* binsA, int* binsB) {
    int e = blockIdx.x * blockDim.x + threadIdx.x;
    if (e < 65536) { binsA[e] = 0; binsB[e] = 0; }
    if (e >= NEDGE) return;
    int s = cur_src[e];
    if (s < 0) return;
    int d = cur_dst[e];
    if (do_remap) {
        int ns = newid[s], nd = newid[d];
        if (ns < 0 || nd < 0) { cur_src[e] = -1; return; }
        s = ns; d = nd;
        cur_src[e] = s; cur_dst[e] = d;
    }
    atomicAdd(&deg_out[s], 1);
    int pos = atomicAdd(&fill[d], 1);
    if (pos < STRIDE) csr_src[(size_t)d * STRIDE + pos] = s;
}

// ---------- GEMM: h_pre(bf16) = X @ W ----------
__global__ __launch_bounds__(256) void k_gemm(
        const float* __restrict__ feat, const float* __restrict__ xprev,
        const int* __restrict__ oldid, const float* __restrict__ garr,
        const float* __restrict__ W, unsigned short* __restrict__ hpre,
        int n, int nprev, int mode) {
    __shared__ float Wt[32][132];
    __shared__ float Xt[64][33];
    int tid = threadIdx.x;
    int r0 = blockIdx.x * 64;
    int c0 = (tid & 7) * 16;
    int rl0 = (tid >> 3) * 2;
    float acc0[16], acc1[16];
#pragma unroll
    for (int c = 0; c < 16; ++c) { acc0[c] = 0.f; acc1[c] = 0.f; }

    for (int kb = 0; kb < 128; kb += 32) {
        {
            int kk = tid >> 3;
            int cc = (tid & 7) * 16;
            const float4* wp = (const float4*)(W + (size_t)(kb + kk) * 128 + cc);
            float4 w0 = wp[0], w1 = wp[1], w2 = wp[2], w3 = wp[3];
            float* dw = &Wt[kk][cc];
            dw[0] = w0.x; dw[1] = w0.y; dw[2] = w0.z; dw[3] = w0.w;
            dw[4] = w1.x; dw[5] = w1.y; dw[6] = w1.z; dw[7] = w1.w;
            dw[8] = w2.x; dw[9] = w2.y; dw[10] = w2.z; dw[11] = w2.w;
            dw[12] = w3.x; dw[13] = w3.y; dw[14] = w3.z; dw[15] = w3.w;
        }
        {
            int rr = tid >> 2;
            int kx = (tid & 3) * 8;
            int gr = r0 + rr;
            float vals[8];
            if (gr < n) {
                if (mode == 0) {
                    const float4* xp = (const float4*)(feat + (size_t)gr * 128 + kb + kx);
                    float4 a = xp[0], bq = xp[1];
                    vals[0] = a.x; vals[1] = a.y; vals[2] = a.z; vals[3] = a.w;
                    vals[4] = bq.x; vals[5] = bq.y; vals[6] = bq.z; vals[7] = bq.w;
                } else {
                    int orow = oldid[gr];
                    float g = garr[gr];
                    if ((unsigned)orow >= (unsigned)nprev) { orow = 0; g = 0.f; }
                    const float4* xp = (const float4*)(xprev + (size_t)orow * 128 + kb + kx);
                    float4 a = xp[0], bq = xp[1];
                    vals[0] = a.x * g; vals[1] = a.y * g; vals[2] = a.z * g; vals[3] = a.w * g;
                    vals[4] = bq.x * g; vals[5] = bq.y * g; vals[6] = bq.z * g; vals[7] = bq.w * g;
                }
            } else {
#pragma unroll
                for (int q2 = 0; q2 < 8; ++q2) vals[q2] = 0.f;
            }
            float* dx = &Xt[rr][kx];
#pragma unroll
            for (int q2 = 0; q2 < 8; ++q2) dx[q2] = vals[q2];
        }
        __syncthreads();
#pragma unroll 4
        for (int kk = 0; kk < 32; ++kk) {
            float x0 = Xt[rl0][kk], x1 = Xt[rl0 + 1][kk];
#pragma unroll
            for (int c = 0; c < 16; ++c) {
                float wv = Wt[kk][c0 + c];
                acc0[c] = fmaf(x0, wv, acc0[c]);
                acc1[c] = fmaf(x1, wv, acc1[c]);
            }
        }
        __syncthreads();
    }
    int gr0 = r0 + rl0;
    if (gr0 < n) {
        unsigned short tmp[16];
#pragma unroll
        for (int c = 0; c < 16; ++c) tmp[c] = f2b(acc0[c]);
        uint4* op = (uint4*)(hpre + (size_t)gr0 * 128 + c0);
        op[0] = ((uint4*)tmp)[0]; op[1] = ((uint4*)tmp)[1];
    }
    int gr1 = gr0 + 1;
    if (gr1 < n) {
        unsigned short tmp[16];
#pragma unroll
        for (int c = 0; c < 16; ++c) tmp[c] = f2b(acc1[c]);
        uint4* op = (uint4*)(hpre + (size_t)gr1 * 128 + c0);
        op[0] = ((uint4*)tmp)[0]; op[1] = ((uint4*)tmp)[1];
    }
}

// ---------- edge aggregation (bf16 gather, fp32 accumulate) ----------
__global__ __launch_bounds__(256) void k_agg_conv(
        const unsigned short* __restrict__ hpre, const int* __restrict__ fill,
        const int* __restrict__ deg_out, const int* __restrict__ csr_src,
        const float* __restrict__ cb, const float* __restrict__ sW,
        float* __restrict__ hpost, float* __restrict__ hs, int n) {
    int wid = threadIdx.x >> 6;
    int lane = threadIdx.x & 63;
    int d = blockIdx.x * 4 + wid;
    if (d >= n) return;
    int degin = fill[d];
    int cnt = min(degin, STRIDE);
    const int* bp = csr_src + (size_t)d * STRIDE;
    float a0 = 0.f, a1 = 0.f;
    int j = 0;
    for (; j + 2 <= cnt; j += 2) {
        int s0 = bp[j], s1 = bp[j + 1];
        float w0 = rsqrtf(fmaxf((float)deg_out[s0], 1.f));
        float w1 = rsqrtf(fmaxf((float)deg_out[s1], 1.f));
        ushort2 u0 = ((const ushort2*)(hpre + (size_t)s0 * 128))[lane];
        ushort2 u1 = ((const ushort2*)(hpre + (size_t)s1 * 128))[lane];
        a0 = fmaf(b2f(u0.x), w0, a0); a0 = fmaf(b2f(u1.x), w1, a0);
        a1 = fmaf(b2f(u0.y), w0, a1); a1 = fmaf(b2f(u1.y), w1, a1);
    }
    if (j < cnt) {
        int s0 = bp[j];
        float w0 = rsqrtf(fmaxf((float)deg_out[s0], 1.f));
        ushort2 u0 = ((const ushort2*)(hpre + (size_t)s0 * 128))[lane];
        a0 = fmaf(b2f(u0.x), w0, a0);
        a1 = fmaf(b2f(u0.y), w0, a1);
    }
    float nd2 = rsqrtf(fmaxf((float)degin, 1.f));
    int c0 = lane * 2;
    float h0 = fmaxf(fmaf(a0, nd2, cb[c0]), 0.f);
    float h1 = fmaxf(fmaf(a1, nd2, cb[c0 + 1]), 0.f);
    ((float2*)(hpost + (size_t)d * 128))[lane] = make_float2(h0, h1);
    float v = h0 * sW[c0] + h1 * sW[c0 + 1];
#pragma unroll
    for (int off = 32; off; off >>= 1) v += __shfl_down(v, off);
    if (lane == 0) hs[d] = v;
}

// ---------- score + radix histogram pass 1 (top 16 bits) fused ----------
__global__ void k_score_hist(const float* __restrict__ hs, const int* __restrict__ fill,
                             const int* __restrict__ deg_out, const int* __restrict__ csr_src,
                             const float* __restrict__ sb, float* score, int* binsA, int n) {
    int d = blockIdx.x * blockDim.x + threadIdx.x;
    if (d >= n) return;
    int degin = fill[d];
    int cnt = min(degin, STRIDE);
    const int* bp = csr_src + (size_t)d * STRIDE;
    float sum = 0.f;
    for (int j = 0; j < cnt; ++j) {
        int s = bp[j];
        sum = fmaf(hs[s], rsqrtf(fmaxf((float)deg_out[s], 1.f)), sum);
    }
    float sc = rsqrtf(fmaxf((float)degin, 1.f)) * sum + sb[0];
    score[d] = sc;
    atomicAdd(&binsA[fkey(sc) >> 16], 1);
}

// ---------- radix histogram pass 2 (low 16 bits of matching prefix) ----------
__global__ void k_rhist2(const float* __restrict__ score, const int* __restrict__ ctrl,
                         int n, int* binsB) {
    unsigned p16 = (unsigned)ctrl[3];
    for (int i = blockIdx.x * 256 + threadIdx.x; i < n; i += gridDim.x * 256) {
        unsigned u = fkey(score[i]);
        if ((u >> 16) == p16) atomicAdd(&binsB[u & 0xFFFFu], 1);
    }
}

// ---------- hierarchical chunk sums: 64 blocks x 256 thr, int4 coalesced ----------
__global__ void k_rsum(const int* __restrict__ bins, int* gsum) {
    __shared__ int wsum[4];
    int b = blockIdx.x, t = threadIdx.x;  // 256
    const int4* p4 = (const int4*)(bins + (size_t)b * 1024);
    int4 q = p4[t];
    int s = q.x + q.y + q.z + q.w;
    int lane = t & 63, w = t >> 6;
#pragma unroll
    for (int off = 32; off; off >>= 1) s += __shfl_down(s, off);
    if (lane == 0) wsum[w] = s;
    __syncthreads();
    if (t == 0) gsum[b] = wsum[0] + wsum[1] + wsum[2] + wsum[3];
}

// ---------- radix pick: 1 block 1024 thr, coalesced chunk scan ----------
// stage0: ctrl[3]=prefix16, ctrl[4]=kneed2.  stage1: ctrl[0]=T, ctrl[2]=needEq.
__global__ void k_rpick(int stage, int k0, int* ctrl,
                        const int* __restrict__ bins, const int* __restrict__ gsum) {
    __shared__ int gs[64];
    __shared__ int arr[1024];
    __shared__ int wsum[16];
    __shared__ int sChunk, sKrem;
    int t = threadIdx.x;  // 1024
    if (t < 64) gs[t] = gsum[t];
    __syncthreads();
    if (t == 0) {
        int kneed = (stage == 0) ? k0 : ctrl[4];
        int cum = 0, c = 63;
        for (; c >= 1; --c) { int v = gs[c]; if (cum + v >= kneed) break; cum += v; }
        sChunk = c; sKrem = kneed - cum;
    }
    __syncthreads();
    int c = sChunk;
    int v = bins[(size_t)c * 1024 + t];
    arr[t] = v;
    int lane = t & 63, w = t >> 6;
    int s = v;
#pragma unroll
    for (int off = 32; off; off >>= 1) s += __shfl_down(s, off);
    if (lane == 0) wsum[w] = s;
    __syncthreads();
    if (t == 0) {
        int kneed = sKrem;
        int cum = 0, w2 = 15;
        for (; w2 >= 1; --w2) { int vv = wsum[w2]; if (cum + vv >= kneed) break; cum += vv; }
        int j = 63;
        for (; j >= 1; --j) { int vv = arr[w2 * 64 + j]; if (cum + vv >= kneed) break; cum += vv; }
        int bin = c * 1024 + w2 * 64 + j;
        if (stage == 0) { ctrl[3] = bin; ctrl[4] = kneed - cum; }
        else {
            ctrl[0] = (int)((((unsigned)ctrl[3]) << 16) | (unsigned)bin);
            ctrl[2] = kneed - cum;
        }
    }
}

// ---------- parallel compaction ----------
__global__ void k_ccnt(const float* __restrict__ score, const int* __restrict__ ctrl,
                       int n, int* cntG, int* cntE) {
    __shared__ int wG[16], wE[16];
    int b = blockIdx.x;
    int i = b * 1024 + threadIdx.x;
    int lane = threadIdx.x & 63, wid = threadIdx.x >> 6;
    unsigned T = (unsigned)ctrl[0];
    bool inb = (i < n);
    unsigned u = inb ? fkey(score[i]) : 0u;
    bool isG = inb && (u > T);
    bool isE = inb && (u == T);
    unsigned long long mG = __ballot(isG);
    unsigned long long mE = __ballot(isE);
    if (lane == 0) { wG[wid] = __popcll(mG); wE[wid] = __popcll(mE); }
    __syncthreads();
    if (threadIdx.x == 0) {
        int sg = 0, se = 0;
#pragma unroll
        for (int w = 0; w < 16; ++w) { sg += wG[w]; se += wE[w]; }
        cntG[b] = sg; cntE[b] = se;
    }
}

__global__ void k_cscan(const int* __restrict__ cntG, const int* __restrict__ cntE,
                        int* coffG, int* coffE, int B, float* maxbuf) {
    int tid = threadIdx.x;  // 256
    if (tid < 128) maxbuf[tid] = NEG_HUGE;
    if (tid == 0) {
        int rg = 0, re = 0;
        for (int b = 0; b < B; ++b) {
            coffG[b] = rg; coffE[b] = re;
            rg += cntG[b]; re += cntE[b];
        }
    }
}

// emit + zero next-level degree arrays
__global__ void k_cemit(const float* __restrict__ score, const int* __restrict__ ctrl,
                        const int* __restrict__ coffG, const int* __restrict__ coffE,
                        int n, int knext, int* newid, int* oldid, float* garr,
                        int* deg_out, int* fill) {
    __shared__ int wG[16], wE[16];
    int b = blockIdx.x;
    int i = b * 1024 + threadIdx.x;
    if (i < knext) { deg_out[i] = 0; fill[i] = 0; }
    int lane = threadIdx.x & 63, wid = threadIdx.x >> 6;
    unsigned T = (unsigned)ctrl[0];
    int needEq = ctrl[2];
    bool inb = (i < n);
    float sc = inb ? score[i] : 0.f;
    unsigned u = inb ? fkey(sc) : 0u;
    bool isG = inb && (u > T);
    bool isE = inb && (u == T);
    unsigned long long mG = __ballot(isG);
    unsigned long long mE = __ballot(isE);
    if (lane == 0) { wG[wid] = __popcll(mG); wE[wid] = __popcll(mE); }
    __syncthreads();
    unsigned long long below = (1ull << lane) - 1ull;
    int gW = 0, eW = 0;
    for (int w = 0; w < wid; ++w) { gW += wG[w]; eW += wE[w]; }
    int Gb = coffG[b] + gW + __popcll(mG & below);
    int Eb = coffE[b] + eW + __popcll(mE & below);
    if (inb) {
        bool sel = isG || (isE && (Eb < needEq));
        if (sel) {
            int j = Gb + min(Eb, needEq);
            newid[i] = j;
            oldid[j] = i;
            garr[j] = tanhf(sc);
        } else {
            newid[i] = -1;
        }
    }
}

__global__ void k_readout(const float* __restrict__ hpost, const int* __restrict__ oldid,
                          const float* __restrict__ garr, float* finalv, float* maxbuf,
                          int k, int n, float invk) {
    int c = threadIdx.x;  // 128
    float sum = 0.f, mx = NEG_HUGE;
    for (int r = blockIdx.x; r < k; r += gridDim.x) {
        int o = oldid[r];
        if ((unsigned)o >= (unsigned)n) continue;  // insurance
        float g = garr[r];
        float v = hpost[(size_t)o * 128 + c] * g;
        sum += v;
        mx = fmaxf(mx, v);
    }
    atomicAdd(&finalv[c], sum * invk);
    atomicMaxF(&maxbuf[c], mx);
}

// ---------- MLP: 3 parallel kernels ----------
__global__ void k_mlp1(const float* __restrict__ finalv, const float* __restrict__ maxbuf,
                       const float* __restrict__ seq, const float* __restrict__ W1,
                       float* f1raw) {
    int o = threadIdx.x;             // 256
    int j0 = blockIdx.x * 128;       // 10 blocks
    float acc = 0.f;
    for (int jj = 0; jj < 128; ++jj) {
        int j = j0 + jj;
        float fv;
        if (j < 128) fv = finalv[j];
        else if (j < 256) fv = maxbuf[j - 128] + maxbuf[j] + maxbuf[j + 128];
        else fv = seq[j - 256];
        acc = fmaf(fv, W1[(size_t)j * 256 + o], acc);
    }
    atomicAdd(&f1raw[o], acc);
}

__global__ void k_mlp2(const float* __restrict__ f1raw, const float* __restrict__ b1,
                       const float* __restrict__ W2, const float* __restrict__ bb2,
                       float* f2v) {
    __shared__ float f1s[256];
    int t = threadIdx.x;  // 128
    f1s[t] = fmaxf(f1raw[t] + b1[t], 0.f);
    f1s[t + 128] = fmaxf(f1raw[t + 128] + b1[t + 128], 0.f);
    __syncthreads();
    float acc = 0.f;
    for (int j = 0; j < 256; ++j)
        acc = fmaf(f1s[j], W2[(size_t)j * 128 + t], acc);
    f2v[t] = fmaxf(acc + bb2[t], 0.f);
}

__global__ void k_mlp3(const float* __restrict__ f2v, const float* __restrict__ W3,
                       const float* __restrict__ b3, float* out) {
    __shared__ float f2s[128];
    int t = threadIdx.x;  // 128
    f2s[t] = f2v[t];
    __syncthreads();
    int col = blockIdx.x * 128 + t;  // 16 blocks
    float acc = 0.f;
    for (int j = 0; j < 128; ++j)
        acc = fmaf(f2s[j], W3[(size_t)j * 2048 + col], acc);
    out[col] = acc + b3[col];
}

// ---------- host ----------
extern "C" void kernel_launch(void* const* d_in, const int* in_sizes, int n_in,
                              void* d_out, int out_size, void* d_ws, size_t ws_size,
                              hipStream_t stream) {
    (void)in_sizes; (void)n_in; (void)out_size; (void)ws_size;
    const float* feat = (const float*)d_in[0];
    const float* seq  = (const float*)d_in[1];
    const int* src = (const int*)d_in[2];
    const int* dst = (const int*)d_in[3];
    // d_in[4], d_in[5]: label_src/label_dst — dead code in reference, unused.
    const float *cW[3], *cb[3], *sW[3], *sb[3];
    for (int b = 0; b < 3; ++b) {
        cW[b] = (const float*)d_in[6 + 4 * b];
        cb[b] = (const float*)d_in[7 + 4 * b];
        sW[b] = (const float*)d_in[8 + 4 * b];
        sb[b] = (const float*)d_in[9 + 4 * b];
    }
    const float* lin1W = (const float*)d_in[18];
    const float* lin1b = (const float*)d_in[19];
    const float* lin2W = (const float*)d_in[20];
    const float* lin2b = (const float*)d_in[21];
    const float* lin3W = (const float*)d_in[22];
    const float* lin3b = (const float*)d_in[23];
    float* out = (float*)d_out;

    char* p = (char*)d_ws;
    size_t off = 0;
    auto alloc = [&](size_t bytes) -> void* {
        void* r = p + off;
        off = (off + bytes + 255) & ~(size_t)255;
        return r;
    };
    unsigned short* hpre = (unsigned short*)alloc((size_t)N0 * 128 * 2);  // bf16
    float* hpost  = (float*)alloc((size_t)N0 * 128 * 4);
    float* hs     = (float*)alloc((size_t)N0 * 4);
    float* score  = (float*)alloc((size_t)N0 * 4);
    int* deg_out  = (int*)alloc((size_t)N0 * 4);
    int* fill     = (int*)alloc((size_t)N0 * 4);   // = in-degree
    int* cur_src  = (int*)alloc((size_t)NEDGE * 4);
    int* cur_dst  = (int*)alloc((size_t)NEDGE * 4);
    int* csr_src  = (int*)alloc((size_t)N0 * STRIDE * 4);
    int* newid    = (int*)alloc((size_t)N0 * 4);
    int* oldid    = (int*)alloc((size_t)25000 * 4);
    float* garr   = (float*)alloc((size_t)25000 * 4);
    float* maxbuf = (float*)alloc(3 * 128 * 4);
    float* finalv = (float*)alloc(256 * 4);
    float* f1raw  = (float*)alloc(256 * 4);
    float* f2v    = (float*)alloc(128 * 4);
    int* ctrl     = (int*)alloc(64 * 4);
    int* binsA    = (int*)alloc(65536 * 4);
    int* binsB    = (int*)alloc(65536 * 4);
    int* gsum     = (int*)alloc(64 * 4);
    int* cntG     = (int*)alloc(BMAX * 4);
    int* cntE     = (int*)alloc(BMAX * 4);
    int* coffG    = (int*)alloc(BMAX * 4);
    int* coffE    = (int*)alloc(BMAX * 4);

    const int nb[3] = {50000, 25000, 12500};
    const int kb[3] = {25000, 12500, 6250};

    k_init<<<(NEDGE + 255) / 256, 256, 0, stream>>>(src, dst, cur_src, cur_dst, finalv,
                                                    f1raw, deg_out, fill);

    for (int b = 0; b < 3; ++b) {
        int n = nb[b], k = kb[b];
        int B = (n + 1023) / 1024;
        k_fillrm<<<(NEDGE + 255) / 256, 256, 0, stream>>>(cur_src, cur_dst, newid,
                                                          (b > 0) ? 1 : 0, deg_out, fill,
                                                          csr_src, binsA, binsB);
        k_gemm<<<(n + 63) / 64, 256, 0, stream>>>(feat, hpost, oldid, garr, cW[b], hpre, n,
                                                  (b > 0) ? nb[b - 1] : 1, (b == 0) ? 0 : 1);
        k_agg_conv<<<(n + 3) / 4, 256, 0, stream>>>(hpre, fill, deg_out, csr_src, cb[b],
                                                    sW[b], hpost, hs, n);
        k_score_hist<<<(n + 255) / 256, 256, 0, stream>>>(hs, fill, deg_out, csr_src, sb[b],
                                                          score, binsA, n);
        k_rsum<<<64, 256, 0, stream>>>(binsA, gsum);
        k_rpick<<<1, 1024, 0, stream>>>(0, k, ctrl, binsA, gsum);
        k_rhist2<<<128, 256, 0, stream>>>(score, ctrl, n, binsB);
        k_rsum<<<64, 256, 0, stream>>>(binsB, gsum);
        k_rpick<<<1, 1024, 0, stream>>>(1, k, ctrl, binsB, gsum);
        k_ccnt<<<B, 1024, 0, stream>>>(score, ctrl, n, cntG, cntE);
        k_cscan<<<1, 256, 0, stream>>>(cntG, cntE, coffG, coffE, B, maxbuf + b * 128);
        k_cemit<<<B, 1024, 0, stream>>>(score, ctrl, coffG, coffE, n, (b < 2) ? kb[b] : 0,
                                        newid, oldid, garr, deg_out, fill);
        k_readout<<<256, 128, 0, stream>>>(hpost, oldid, garr, finalv, maxbuf + b * 128,
                                           k, n, 1.0f / (float)k);
    }

    k_mlp1<<<10, 256, 0, stream>>>(finalv, maxbuf, seq, lin1W, f1raw);
    k_mlp2<<<1, 128, 0, stream>>>(f1raw, lin1b, lin2W, lin2b, f2v);
    k_mlp3<<<16, 128, 0, stream>>>(f2v, lin3W, lin3b, out);
}